// Round 1
// baseline (1559.899 us; speedup 1.0000x reference)
//
#include <hip/hip_runtime.h>
#include <math.h>

#define E_DIM 1024
#define H_NUM 16
#define HD 64
#define B_NUM 2
#define T_LEN 2048

// ---------------------------------------------------------------------------
// Kernel 1: QKV projection.
// q[h,b,t,i] = sum_e Wq[h,e,i] * x[b,t,e]   (same for k, v)
// Viewed as GEMM: X(4096 x 1024) @ W_h(1024 x 64) per (matrix, head).
// Grid: x = 48 col tiles (3 matrices x 16 heads, each head is one 64-col tile),
//       y = 64 row tiles (rows = b*T + t).
// ---------------------------------------------------------------------------
__global__ __launch_bounds__(256) void qkv_kernel(
    const float* __restrict__ x,
    const float* __restrict__ Wq,
    const float* __restrict__ Wk,
    const float* __restrict__ Wv,
    float* __restrict__ q,
    float* __restrict__ k,
    float* __restrict__ v)
{
    const int ct = blockIdx.x;      // 0..47
    const int m  = ct >> 4;         // 0=q 1=k 2=v
    const int h  = ct & 15;
    const int r0 = blockIdx.y * 64; // row tile base; row = b*T + t

    const float* W = (m == 0 ? Wq : (m == 1 ? Wk : Wv)) + (size_t)h * (E_DIM * HD);
    float* outp = (m == 0 ? q : (m == 1 ? k : v)) + (size_t)h * (B_NUM * T_LEN * HD);

    __shared__ float Xs[64][17];   // 64 rows x 16 k, +1 pad
    __shared__ float Ws[16][64];   // 16 k x 64 cols

    const int tid = threadIdx.x;
    const int tx = tid & 15;
    const int ty = tid >> 4;

    float acc[4][4];
    #pragma unroll
    for (int i = 0; i < 4; i++)
        #pragma unroll
        for (int j = 0; j < 4; j++) acc[i][j] = 0.f;

    for (int k0 = 0; k0 < E_DIM; k0 += 16) {
        #pragma unroll
        for (int j = 0; j < 4; j++) {
            int idx = j * 256 + tid;
            int r = idx >> 4, c = idx & 15;
            Xs[r][c] = x[(size_t)(r0 + r) * E_DIM + k0 + c];
        }
        #pragma unroll
        for (int j = 0; j < 4; j++) {
            int idx = j * 256 + tid;
            int kk = idx >> 6, i = idx & 63;
            Ws[kk][i] = W[(size_t)(k0 + kk) * HD + i];
        }
        __syncthreads();
        #pragma unroll
        for (int kk = 0; kk < 16; kk++) {
            float a[4], bb[4];
            #pragma unroll
            for (int i = 0; i < 4; i++) a[i] = Xs[ty * 4 + i][kk];
            #pragma unroll
            for (int j = 0; j < 4; j++) bb[j] = Ws[kk][tx * 4 + j];
            #pragma unroll
            for (int i = 0; i < 4; i++)
                #pragma unroll
                for (int j = 0; j < 4; j++) acc[i][j] += a[i] * bb[j];
        }
        __syncthreads();
    }

    #pragma unroll
    for (int i = 0; i < 4; i++) {
        int row = r0 + ty * 4 + i;
        #pragma unroll
        for (int j = 0; j < 4; j++) {
            outp[(size_t)row * HD + tx * 4 + j] = acc[i][j];
        }
    }
}

// ---------------------------------------------------------------------------
// Kernel 2: flash-style attention per (h,b), 64 q-rows per block.
// fit = (Q K^T)/sqrt(T); softmax over s; O = softmax @ V.
// Writes attended in [b][t][h*64+i] layout (ready for output projection).
// Grid: x = 32 t-tiles, y = 32 (h,b) pairs.
// ---------------------------------------------------------------------------
__global__ __launch_bounds__(256) void attn_kernel(
    const float* __restrict__ q,
    const float* __restrict__ k,
    const float* __restrict__ v,
    float* __restrict__ att)
{
    const int hb = blockIdx.y;       // 0..31
    const int h = hb >> 1, b = hb & 1;
    const int t0 = blockIdx.x * 64;

    const float* qh = q + (size_t)(h * B_NUM + b) * T_LEN * HD;
    const float* kh = k + (size_t)(h * B_NUM + b) * T_LEN * HD;
    const float* vh = v + (size_t)(h * B_NUM + b) * T_LEN * HD;

    __shared__ float Qs[64][65];
    __shared__ float Ks[64][65];
    __shared__ float Vs[64][65];
    __shared__ float Ps[64][65];
    __shared__ float mS[64], lS[64], aS[64];

    const int tid = threadIdx.x;
    const int tx = tid & 15, ty = tid >> 4;
    const float scale = rsqrtf((float)T_LEN);

    // load Q tile (pre-scaled)
    #pragma unroll
    for (int j = 0; j < 16; j++) {
        int idx = j * 256 + tid;
        int r = idx >> 6, c = idx & 63;
        Qs[r][c] = qh[(size_t)(t0 + r) * HD + c] * scale;
    }
    if (tid < 64) { mS[tid] = -1e30f; lS[tid] = 0.f; }

    float o[4][4];
    #pragma unroll
    for (int i = 0; i < 4; i++)
        #pragma unroll
        for (int j = 0; j < 4; j++) o[i][j] = 0.f;

    for (int st = 0; st < T_LEN / 64; st++) {
        __syncthreads();   // prev iter's Ps/Vs reads done before overwrite
        #pragma unroll
        for (int j = 0; j < 16; j++) {
            int idx = j * 256 + tid;
            int r = idx >> 6, c = idx & 63;
            Ks[r][c] = kh[(size_t)(st * 64 + r) * HD + c];
            Vs[r][c] = vh[(size_t)(st * 64 + r) * HD + c];
        }
        __syncthreads();

        // S = Qs @ Ks^T  (64x64 tile, 4x4 per thread)
        float s[4][4];
        #pragma unroll
        for (int i = 0; i < 4; i++)
            #pragma unroll
            for (int j = 0; j < 4; j++) s[i][j] = 0.f;
        #pragma unroll 8
        for (int d = 0; d < 64; d++) {
            float a[4], bb[4];
            #pragma unroll
            for (int i = 0; i < 4; i++) a[i] = Qs[ty * 4 + i][d];
            #pragma unroll
            for (int j = 0; j < 4; j++) bb[j] = Ks[tx * 4 + j][d];
            #pragma unroll
            for (int i = 0; i < 4; i++)
                #pragma unroll
                for (int j = 0; j < 4; j++) s[i][j] += a[i] * bb[j];
        }
        #pragma unroll
        for (int i = 0; i < 4; i++)
            #pragma unroll
            for (int j = 0; j < 4; j++) Ps[ty * 4 + i][tx * 4 + j] = s[i][j];
        __syncthreads();

        // online softmax row update (one thread per row)
        if (tid < 64) {
            float mo = mS[tid];
            float rm = mo;
            #pragma unroll 8
            for (int c = 0; c < 64; c++) rm = fmaxf(rm, Ps[tid][c]);
            float al = __expf(mo - rm);
            float sum = 0.f;
            #pragma unroll 8
            for (int c = 0; c < 64; c++) {
                float p = __expf(Ps[tid][c] - rm);
                Ps[tid][c] = p;
                sum += p;
            }
            lS[tid] = lS[tid] * al + sum;
            mS[tid] = rm;
            aS[tid] = al;
        }
        __syncthreads();

        // O = O*alpha + P @ V
        float al[4];
        #pragma unroll
        for (int i = 0; i < 4; i++) al[i] = aS[ty * 4 + i];
        #pragma unroll
        for (int i = 0; i < 4; i++)
            #pragma unroll
            for (int j = 0; j < 4; j++) o[i][j] *= al[i];
        #pragma unroll 8
        for (int sx = 0; sx < 64; sx++) {
            float p[4], vv[4];
            #pragma unroll
            for (int i = 0; i < 4; i++) p[i] = Ps[ty * 4 + i][sx];
            #pragma unroll
            for (int j = 0; j < 4; j++) vv[j] = Vs[sx][tx * 4 + j];
            #pragma unroll
            for (int i = 0; i < 4; i++)
                #pragma unroll
                for (int j = 0; j < 4; j++) o[i][j] += p[i] * vv[j];
        }
    }
    __syncthreads();

    #pragma unroll
    for (int i = 0; i < 4; i++) {
        int r = ty * 4 + i;
        float inv = 1.f / lS[r];
        #pragma unroll
        for (int j = 0; j < 4; j++) {
            att[(size_t)(b * T_LEN + t0 + r) * E_DIM + h * HD + tx * 4 + j] = o[i][j] * inv;
        }
    }
}

// ---------------------------------------------------------------------------
// Kernel 3: output projection. out = A(4096x1024) @ Wo^T (Wo is [out,in]).
// ---------------------------------------------------------------------------
__global__ __launch_bounds__(256) void outproj_kernel(
    const float* __restrict__ A,
    const float* __restrict__ Wo,
    float* __restrict__ out)
{
    const int c0 = blockIdx.x * 64;
    const int r0 = blockIdx.y * 64;

    __shared__ float As[64][17];
    __shared__ float Ws[64][17];   // Ws[c][kk] = Wo[c0+c][k0+kk]

    const int tid = threadIdx.x;
    const int tx = tid & 15, ty = tid >> 4;

    float acc[4][4];
    #pragma unroll
    for (int i = 0; i < 4; i++)
        #pragma unroll
        for (int j = 0; j < 4; j++) acc[i][j] = 0.f;

    for (int k0 = 0; k0 < E_DIM; k0 += 16) {
        #pragma unroll
        for (int j = 0; j < 4; j++) {
            int idx = j * 256 + tid;
            int r = idx >> 4, c = idx & 15;
            As[r][c] = A[(size_t)(r0 + r) * E_DIM + k0 + c];
        }
        #pragma unroll
        for (int j = 0; j < 4; j++) {
            int idx = j * 256 + tid;
            int c = idx >> 4, kk = idx & 15;
            Ws[c][kk] = Wo[(size_t)(c0 + c) * E_DIM + k0 + kk];
        }
        __syncthreads();
        #pragma unroll
        for (int kk = 0; kk < 16; kk++) {
            float a[4], bb[4];
            #pragma unroll
            for (int i = 0; i < 4; i++) a[i] = As[ty * 4 + i][kk];
            #pragma unroll
            for (int j = 0; j < 4; j++) bb[j] = Ws[tx * 4 + j][kk];
            #pragma unroll
            for (int i = 0; i < 4; i++)
                #pragma unroll
                for (int j = 0; j < 4; j++) acc[i][j] += a[i] * bb[j];
        }
        __syncthreads();
    }

    #pragma unroll
    for (int i = 0; i < 4; i++) {
        int row = r0 + ty * 4 + i;
        #pragma unroll
        for (int j = 0; j < 4; j++) {
            out[(size_t)row * E_DIM + c0 + tx * 4 + j] = acc[i][j];
        }
    }
}

extern "C" void kernel_launch(void* const* d_in, const int* in_sizes, int n_in,
                              void* d_out, int out_size, void* d_ws, size_t ws_size,
                              hipStream_t stream)
{
    const float* x  = (const float*)d_in[0];
    const float* Wq = (const float*)d_in[1];
    const float* Wk = (const float*)d_in[2];
    const float* Wv = (const float*)d_in[3];
    const float* Wo = (const float*)d_in[4];
    float* out = (float*)d_out;

    const size_t qkv_elems = (size_t)H_NUM * B_NUM * T_LEN * HD; // 4,194,304
    float* ws = (float*)d_ws;
    float* q   = ws;
    float* k   = q + qkv_elems;
    float* v   = k + qkv_elems;
    float* att = v + qkv_elems;

    dim3 g1(48, (B_NUM * T_LEN) / 64);
    qkv_kernel<<<g1, 256, 0, stream>>>(x, Wq, Wk, Wv, q, k, v);

    dim3 g2(T_LEN / 64, H_NUM * B_NUM);
    attn_kernel<<<g2, 256, 0, stream>>>(q, k, v, att);

    dim3 g3(E_DIM / 64, (B_NUM * T_LEN) / 64);
    outproj_kernel<<<g3, 256, 0, stream>>>(att, Wo, out);
}

// Round 2
// 796.544 us; speedup vs baseline: 1.9583x; 1.9583x over previous
//
#include <hip/hip_runtime.h>
#include <math.h>

#define E_DIM 1024
#define H_NUM 16
#define HD 64
#define B_NUM 2
#define T_LEN 2048

typedef short bf16x8 __attribute__((ext_vector_type(8)));
typedef float f32x4 __attribute__((ext_vector_type(4)));

#define MFMA16(a, b, c) __builtin_amdgcn_mfma_f32_16x16x32_bf16(a, b, c, 0, 0, 0)

__device__ __forceinline__ unsigned short f2bf(float f) {
    unsigned u = __float_as_uint(f);
    u += 0x7FFFu + ((u >> 16) & 1u);   // RNE
    return (unsigned short)(u >> 16);
}
__device__ __forceinline__ float bf2f(unsigned short b) {
    return __uint_as_float(((unsigned)b) << 16);
}

// ---------------------------------------------------------------------------
// Kernel 1: QKV projection (fp32 vector, unchanged this round).
// ---------------------------------------------------------------------------
__global__ __launch_bounds__(256) void qkv_kernel(
    const float* __restrict__ x,
    const float* __restrict__ Wq,
    const float* __restrict__ Wk,
    const float* __restrict__ Wv,
    float* __restrict__ q,
    float* __restrict__ k,
    float* __restrict__ v)
{
    const int ct = blockIdx.x;      // 0..47
    const int m  = ct >> 4;         // 0=q 1=k 2=v
    const int h  = ct & 15;
    const int r0 = blockIdx.y * 64;

    const float* W = (m == 0 ? Wq : (m == 1 ? Wk : Wv)) + (size_t)h * (E_DIM * HD);
    float* outp = (m == 0 ? q : (m == 1 ? k : v)) + (size_t)h * (B_NUM * T_LEN * HD);

    __shared__ float Xs[64][17];
    __shared__ float Ws[16][64];

    const int tid = threadIdx.x;
    const int tx = tid & 15;
    const int ty = tid >> 4;

    float acc[4][4];
    #pragma unroll
    for (int i = 0; i < 4; i++)
        #pragma unroll
        for (int j = 0; j < 4; j++) acc[i][j] = 0.f;

    for (int k0 = 0; k0 < E_DIM; k0 += 16) {
        #pragma unroll
        for (int j = 0; j < 4; j++) {
            int idx = j * 256 + tid;
            int r = idx >> 4, c = idx & 15;
            Xs[r][c] = x[(size_t)(r0 + r) * E_DIM + k0 + c];
        }
        #pragma unroll
        for (int j = 0; j < 4; j++) {
            int idx = j * 256 + tid;
            int kk = idx >> 6, i = idx & 63;
            Ws[kk][i] = W[(size_t)(k0 + kk) * HD + i];
        }
        __syncthreads();
        #pragma unroll
        for (int kk = 0; kk < 16; kk++) {
            float a[4], bb[4];
            #pragma unroll
            for (int i = 0; i < 4; i++) a[i] = Xs[ty * 4 + i][kk];
            #pragma unroll
            for (int j = 0; j < 4; j++) bb[j] = Ws[kk][tx * 4 + j];
            #pragma unroll
            for (int i = 0; i < 4; i++)
                #pragma unroll
                for (int j = 0; j < 4; j++) acc[i][j] += a[i] * bb[j];
        }
        __syncthreads();
    }

    #pragma unroll
    for (int i = 0; i < 4; i++) {
        int row = r0 + ty * 4 + i;
        #pragma unroll
        for (int j = 0; j < 4; j++) {
            outp[(size_t)row * HD + tx * 4 + j] = acc[i][j];
        }
    }
}

// ---------------------------------------------------------------------------
// Kernel 2: flash attention, bf16 MFMA with hi/lo-split QK^T.
// All LDS operand buffers are in MFMA fragment order:
//   chunk index = ((tile*2 + kstep)*64 + lane), each chunk = 8 bf16 = 16B.
//   A-frag: lane holds A[m=lane&15][k=(lane>>4)*8+j]   (m97/m120-verified)
//   B-frag: lane holds B[k=(lane>>4)*8+j][n=lane&15]
//   C/D   : lane holds D[row=(lane>>4)*4+reg][col=lane&15]
// ---------------------------------------------------------------------------
__global__ __launch_bounds__(256) void attn_kernel(
    const float* __restrict__ q,
    const float* __restrict__ k,
    const float* __restrict__ v,
    float* __restrict__ att)
{
    const int hb = blockIdx.y;       // 0..31
    const int h = hb >> 1, b = hb & 1;
    const int t0 = blockIdx.x * 64;

    const float* qh = q + (size_t)(h * B_NUM + b) * T_LEN * HD;
    const float* kh = k + (size_t)(h * B_NUM + b) * T_LEN * HD;
    const float* vh = v + (size_t)(h * B_NUM + b) * T_LEN * HD;

    // fragment-order LDS buffers, 8KB each, 48KB total -> 3 blocks/CU
    __shared__ __align__(16) short AQh[4096], AQl[4096];   // Q hi/lo  [w][ks][lane][8]
    __shared__ __align__(16) short BKh[4096], BKl[4096];   // K hi/lo  [nt][ks][lane][8]
    __shared__ __align__(16) short BV[4096];               // V        [it][ks][lane][8]
    __shared__ __align__(16) short AP[4096];               // P        [w][ks][lane][8]

    const int tid  = threadIdx.x;
    const int lane = tid & 63;
    const int w    = tid >> 6;      // wave id 0..3 -> rows 16w..16w+15
    const int qd   = lane >> 4;     // quad 0..3
    const int n16  = lane & 15;

    const float scale = 0.02209708691f;  // 1/sqrt(2048)

    // ---- stage Q (scaled, hi/lo split), once per block ----
    #pragma unroll
    for (int rep = 0; rep < 2; rep++) {
        int c0 = tid + rep * 256;            // 0..511
        int wt = c0 >> 7, ks = (c0 >> 6) & 1, lp = c0 & 63;
        int m = lp & 15, qq = lp >> 4;
        const float* src = &qh[(size_t)(t0 + wt * 16 + m) * HD + ks * 32 + qq * 8];
        float4 f0 = *(const float4*)&src[0];
        float4 f1 = *(const float4*)&src[4];
        float fv[8] = {f0.x, f0.y, f0.z, f0.w, f1.x, f1.y, f1.z, f1.w};
        bf16x8 hv, lv;
        #pragma unroll
        for (int j = 0; j < 8; j++) {
            float f = fv[j] * scale;
            unsigned short hi = f2bf(f);
            hv[j] = (short)hi;
            lv[j] = (short)f2bf(f - bf2f(hi));
        }
        *(bf16x8*)&AQh[c0 * 8] = hv;
        *(bf16x8*)&AQl[c0 * 8] = lv;
    }

    f32x4 o[4];
    #pragma unroll
    for (int c = 0; c < 4; c++) o[c] = (f32x4){0.f, 0.f, 0.f, 0.f};
    float mr[4] = {-1e30f, -1e30f, -1e30f, -1e30f};
    float lr[4] = {0.f, 0.f, 0.f, 0.f};

    bf16x8 ones;
    #pragma unroll
    for (int j = 0; j < 8; j++) ones[j] = (short)0x3F80;  // bf16 1.0

    for (int st = 0; st < T_LEN / 64; st++) {
        __syncthreads();   // prev-iter PV reads of BV/AP done

        // ---- stage K tile (hi/lo, B-frag order) ----
        #pragma unroll
        for (int rep = 0; rep < 2; rep++) {
            int c0 = tid + rep * 256;
            int nt = c0 >> 7, ks = (c0 >> 6) & 1, lp = c0 & 63;
            int n = lp & 15, qq = lp >> 4;
            const float* src = &kh[(size_t)(st * 64 + nt * 16 + n) * HD + ks * 32 + qq * 8];
            float4 f0 = *(const float4*)&src[0];
            float4 f1 = *(const float4*)&src[4];
            float fv[8] = {f0.x, f0.y, f0.z, f0.w, f1.x, f1.y, f1.z, f1.w};
            bf16x8 hv, lv;
            #pragma unroll
            for (int j = 0; j < 8; j++) {
                unsigned short hi = f2bf(fv[j]);
                hv[j] = (short)hi;
                lv[j] = (short)f2bf(fv[j] - bf2f(hi));
            }
            *(bf16x8*)&BKh[c0 * 8] = hv;
            *(bf16x8*)&BKl[c0 * 8] = lv;
        }
        // ---- stage V tile (B-frag order: lane holds V[k=qq*8+j][n]) ----
        #pragma unroll
        for (int rep = 0; rep < 2; rep++) {
            int c0 = tid + rep * 256;
            int it = c0 >> 7, ks = (c0 >> 6) & 1, lp = c0 & 63;
            int n = lp & 15, qq = lp >> 4;
            bf16x8 vv;
            #pragma unroll
            for (int j = 0; j < 8; j++) {
                vv[j] = (short)f2bf(vh[(size_t)(st * 64 + ks * 32 + qq * 8 + j) * HD + it * 16 + n]);
            }
            *(bf16x8*)&BV[c0 * 8] = vv;
        }
        __syncthreads();

        // ---- S = Q K^T (hi/lo: 3 MFMA terms) ----
        f32x4 s[4];
        #pragma unroll
        for (int c = 0; c < 4; c++) s[c] = (f32x4){0.f, 0.f, 0.f, 0.f};
        #pragma unroll
        for (int ks = 0; ks < 2; ks++) {
            bf16x8 ah = *(bf16x8*)&AQh[((w * 2 + ks) * 64 + lane) * 8];
            bf16x8 al = *(bf16x8*)&AQl[((w * 2 + ks) * 64 + lane) * 8];
            #pragma unroll
            for (int c = 0; c < 4; c++) {
                bf16x8 bh = *(bf16x8*)&BKh[((c * 2 + ks) * 64 + lane) * 8];
                bf16x8 bl = *(bf16x8*)&BKl[((c * 2 + ks) * 64 + lane) * 8];
                s[c] = MFMA16(ah, bh, s[c]);
                s[c] = MFMA16(al, bh, s[c]);
                s[c] = MFMA16(ah, bl, s[c]);
            }
        }

        // ---- online softmax (row = qd*4 + r, replicated over 16 col-lanes) ----
        float rm[4];
        #pragma unroll
        for (int r = 0; r < 4; r++)
            rm[r] = fmaxf(fmaxf(s[0][r], s[1][r]), fmaxf(s[2][r], s[3][r]));
        #pragma unroll
        for (int r = 0; r < 4; r++) {
            rm[r] = fmaxf(rm[r], __shfl_xor(rm[r], 1));
            rm[r] = fmaxf(rm[r], __shfl_xor(rm[r], 2));
            rm[r] = fmaxf(rm[r], __shfl_xor(rm[r], 4));
            rm[r] = fmaxf(rm[r], __shfl_xor(rm[r], 8));
        }
        float al4[4];
        #pragma unroll
        for (int r = 0; r < 4; r++) {
            float nm = fmaxf(mr[r], rm[r]);
            al4[r] = __expf(mr[r] - nm);
            mr[r] = nm;
        }
        // P = exp(S - m), write bf16 into A-frag-order buffer
        #pragma unroll
        for (int c = 0; c < 4; c++) {
            #pragma unroll
            for (int r = 0; r < 4; r++) {
                float p = __expf(s[c][r] - mr[r]);
                int col = c * 16 + n16;
                int ks = col >> 5, qp = (col >> 3) & 3, j = col & 7;
                int lp = (qp << 4) | (qd * 4 + r);
                AP[((w * 2 + ks) * 64 + lp) * 8 + j] = (short)f2bf(p);
            }
        }
        // rescale O
        #pragma unroll
        for (int c = 0; c < 4; c++)
            #pragma unroll
            for (int r = 0; r < 4; r++) o[c][r] *= al4[r];
        __syncthreads();

        // ---- O += P V ; row-sum via ones-MFMA ----
        bf16x8 ap0 = *(bf16x8*)&AP[((w * 2 + 0) * 64 + lane) * 8];
        bf16x8 ap1 = *(bf16x8*)&AP[((w * 2 + 1) * 64 + lane) * 8];
        f32x4 sm = (f32x4){0.f, 0.f, 0.f, 0.f};
        sm = MFMA16(ap0, ones, sm);
        sm = MFMA16(ap1, ones, sm);
        #pragma unroll
        for (int c = 0; c < 4; c++) {
            bf16x8 bv0 = *(bf16x8*)&BV[((c * 2 + 0) * 64 + lane) * 8];
            bf16x8 bv1 = *(bf16x8*)&BV[((c * 2 + 1) * 64 + lane) * 8];
            o[c] = MFMA16(ap0, bv0, o[c]);
            o[c] = MFMA16(ap1, bv1, o[c]);
        }
        #pragma unroll
        for (int r = 0; r < 4; r++) lr[r] = lr[r] * al4[r] + sm[r];
    }

    // ---- epilogue: O / l, write att in [b][t][h*64+i] layout ----
    float inv[4];
    #pragma unroll
    for (int r = 0; r < 4; r++) inv[r] = 1.f / lr[r];
    #pragma unroll
    for (int c = 0; c < 4; c++) {
        #pragma unroll
        for (int r = 0; r < 4; r++) {
            int row = t0 + w * 16 + qd * 4 + r;
            att[(size_t)(b * T_LEN + row) * E_DIM + h * HD + c * 16 + n16] = o[c][r] * inv[r];
        }
    }
}

// ---------------------------------------------------------------------------
// Kernel 3: output projection (fp32 vector, unchanged this round).
// ---------------------------------------------------------------------------
__global__ __launch_bounds__(256) void outproj_kernel(
    const float* __restrict__ A,
    const float* __restrict__ Wo,
    float* __restrict__ out)
{
    const int c0 = blockIdx.x * 64;
    const int r0 = blockIdx.y * 64;

    __shared__ float As[64][17];
    __shared__ float Ws[64][17];

    const int tid = threadIdx.x;
    const int tx = tid & 15, ty = tid >> 4;

    float acc[4][4];
    #pragma unroll
    for (int i = 0; i < 4; i++)
        #pragma unroll
        for (int j = 0; j < 4; j++) acc[i][j] = 0.f;

    for (int k0 = 0; k0 < E_DIM; k0 += 16) {
        #pragma unroll
        for (int j = 0; j < 4; j++) {
            int idx = j * 256 + tid;
            int r = idx >> 4, c = idx & 15;
            As[r][c] = A[(size_t)(r0 + r) * E_DIM + k0 + c];
        }
        #pragma unroll
        for (int j = 0; j < 4; j++) {
            int idx = j * 256 + tid;
            int c = idx >> 4, kk = idx & 15;
            Ws[c][kk] = Wo[(size_t)(c0 + c) * E_DIM + k0 + kk];
        }
        __syncthreads();
        #pragma unroll
        for (int kk = 0; kk < 16; kk++) {
            float a[4], bb[4];
            #pragma unroll
            for (int i = 0; i < 4; i++) a[i] = As[ty * 4 + i][kk];
            #pragma unroll
            for (int j = 0; j < 4; j++) bb[j] = Ws[tx * 4 + j][kk];
            #pragma unroll
            for (int i = 0; i < 4; i++)
                #pragma unroll
                for (int j = 0; j < 4; j++) acc[i][j] += a[i] * bb[j];
        }
        __syncthreads();
    }

    #pragma unroll
    for (int i = 0; i < 4; i++) {
        int row = r0 + ty * 4 + i;
        #pragma unroll
        for (int j = 0; j < 4; j++) {
            out[(size_t)row * E_DIM + c0 + tx * 4 + j] = acc[i][j];
        }
    }
}

extern "C" void kernel_launch(void* const* d_in, const int* in_sizes, int n_in,
                              void* d_out, int out_size, void* d_ws, size_t ws_size,
                              hipStream_t stream)
{
    const float* x  = (const float*)d_in[0];
    const float* Wq = (const float*)d_in[1];
    const float* Wk = (const float*)d_in[2];
    const float* Wv = (const float*)d_in[3];
    const float* Wo = (const float*)d_in[4];
    float* out = (float*)d_out;

    const size_t qkv_elems = (size_t)H_NUM * B_NUM * T_LEN * HD;
    float* ws = (float*)d_ws;
    float* q   = ws;
    float* k   = q + qkv_elems;
    float* v   = k + qkv_elems;
    float* att = v + qkv_elems;

    dim3 g1(48, (B_NUM * T_LEN) / 64);
    qkv_kernel<<<g1, 256, 0, stream>>>(x, Wq, Wk, Wv, q, k, v);

    dim3 g2(T_LEN / 64, H_NUM * B_NUM);
    attn_kernel<<<g2, 256, 0, stream>>>(q, k, v, att);

    dim3 g3(E_DIM / 64, (B_NUM * T_LEN) / 64);
    outproj_kernel<<<g3, 256, 0, stream>>>(att, Wo, out);
}

// Round 3
// 370.090 us; speedup vs baseline: 4.2149x; 2.1523x over previous
//
#include <hip/hip_runtime.h>
#include <math.h>

#define E_DIM 1024
#define H_NUM 16
#define HD 64
#define B_NUM 2
#define T_LEN 2048

typedef unsigned short u16;
typedef short bf16x8 __attribute__((ext_vector_type(8)));
typedef float f32x4 __attribute__((ext_vector_type(4)));
typedef unsigned short u16x4 __attribute__((ext_vector_type(4)));

#define MFMA16(a, b, c) __builtin_amdgcn_mfma_f32_16x16x32_bf16(a, b, c, 0, 0, 0)

__device__ __forceinline__ u16 f2bf(float f) {
    unsigned u = __float_as_uint(f);
    u += 0x7FFFu + ((u >> 16) & 1u);   // RNE
    return (u16)(u >> 16);
}
__device__ __forceinline__ float bf2f(u16 b) {
    return __uint_as_float(((unsigned)b) << 16);
}
// async global->LDS 16B copy. LDS dest must be wave-uniform base + lane*16;
// all call sites index LDS chunks linearly in tid, which satisfies that.
__device__ __forceinline__ void gl_lds16(const void* g, void* l) {
    __builtin_amdgcn_global_load_lds(
        (const __attribute__((address_space(1))) unsigned int*)g,
        (__attribute__((address_space(3))) unsigned int*)l, 16, 0, 0);
}

// ---------------------------------------------------------------------------
// convert x (fp32 [4096][1024]) -> xh, xl bf16 hi/lo, same layout
// ---------------------------------------------------------------------------
__global__ __launch_bounds__(256) void convert_x_kernel(
    const float* __restrict__ x, u16* __restrict__ xh, u16* __restrict__ xl)
{
    int i = (blockIdx.x * 256 + threadIdx.x) * 4;
    float4 f = *(const float4*)&x[i];
    float fv[4] = {f.x, f.y, f.z, f.w};
    u16x4 h, l;
    #pragma unroll
    for (int j = 0; j < 4; j++) {
        u16 hi = f2bf(fv[j]);
        h[j] = hi;
        l[j] = f2bf(fv[j] - bf2f(hi));
    }
    *(u16x4*)&xh[i] = h;
    *(u16x4*)&xl[i] = l;
}

// ---------------------------------------------------------------------------
// convert Wq/Wk/Wv ([16][1024][64] each) -> wth/wtl [3072][1024] bf16,
// WT[col=m*1024+h*64+i][e] = Wm[h][e][i]   (transpose via LDS tile)
// grid: 768 blocks = m(3) x h(16) x etile(16)
// ---------------------------------------------------------------------------
__global__ __launch_bounds__(256) void convert_w_kernel(
    const float* __restrict__ Wq, const float* __restrict__ Wk, const float* __restrict__ Wv,
    u16* __restrict__ wth, u16* __restrict__ wtl)
{
    const int bx = blockIdx.x;
    const int m = bx >> 8, h = (bx >> 4) & 15, e0 = (bx & 15) * 64;
    const float* W = (m == 0 ? Wq : (m == 1 ? Wk : Wv));

    __shared__ u16 Th[64][65];
    __shared__ u16 Tl[64][65];
    const int tid = threadIdx.x;

    #pragma unroll
    for (int j = 0; j < 16; j++) {
        int idx = j * 256 + tid;
        int e = idx >> 6, i = idx & 63;
        float f = W[((size_t)h * E_DIM + e0 + e) * HD + i];
        u16 hi = f2bf(f);
        Th[i][e] = hi;
        Tl[i][e] = f2bf(f - bf2f(hi));
    }
    __syncthreads();
    #pragma unroll
    for (int j = 0; j < 16; j++) {
        int idx = j * 256 + tid;
        int i = idx >> 6, e = idx & 63;
        size_t o = (size_t)(m * 1024 + h * 64 + i) * E_DIM + e0 + e;
        wth[o] = Th[i][e];
        wtl[o] = Tl[i][e];
    }
}

// ---------------------------------------------------------------------------
// convert Wo (fp32 [1024][1024]) -> wob bf16 same layout
// ---------------------------------------------------------------------------
__global__ __launch_bounds__(256) void convert_wo_kernel(
    const float* __restrict__ Wo, u16* __restrict__ wob)
{
    int i = (blockIdx.x * 256 + threadIdx.x) * 4;
    float4 f = *(const float4*)&Wo[i];
    float fv[4] = {f.x, f.y, f.z, f.w};
    u16x4 h;
    #pragma unroll
    for (int j = 0; j < 4; j++) h[j] = f2bf(fv[j]);
    *(u16x4*)&wob[i] = h;
}

// ---------------------------------------------------------------------------
// Fused QKV GEMM: C(4096 x 3072) = X(4096x1024) @ WT^T, bf16 MFMA,
// 3-term hi/lo for q/k columns, 1-term for v columns.
// Epilogue: q,k -> hi/lo bf16 [h][b][t][d] (q pre-scaled by 1/sqrt(T));
//           v -> plain bf16 transposed [h][b][d][t].
// grid (24, 32), 256 threads (4 waves in 2x2 arrangement over 128x128 tile).
// ---------------------------------------------------------------------------
__global__ __launch_bounds__(256) void qkv_mfma_kernel(
    const u16* __restrict__ xh, const u16* __restrict__ xl,
    const u16* __restrict__ wth, const u16* __restrict__ wtl,
    u16* __restrict__ qh, u16* __restrict__ ql,
    u16* __restrict__ kh, u16* __restrict__ kl,
    u16* __restrict__ vt)
{
    const int c0 = blockIdx.x * 128;
    const int r0 = blockIdx.y * 128;
    const int m  = c0 >> 10;            // 0=q 1=k 2=v (128 | 1024 so no straddle)
    const bool lo = (m != 2);

    __shared__ __align__(16) u16 Ah[4096], Al[4096];   // 8KB each
    __shared__ __align__(16) u16 Bh[4096], Bl[4096];

    const int tid = threadIdx.x;
    const int w = tid >> 6, lane = tid & 63;
    const int qd = lane >> 4, n16 = lane & 15;
    const int wr = w >> 1, wc = w & 1;

    f32x4 acc[4][4];
    #pragma unroll
    for (int i = 0; i < 4; i++)
        #pragma unroll
        for (int j = 0; j < 4; j++) acc[i][j] = (f32x4){0.f, 0.f, 0.f, 0.f};

    for (int k0 = 0; k0 < E_DIM; k0 += 32) {
        __syncthreads();
        #pragma unroll
        for (int rep = 0; rep < 2; rep++) {
            int c = rep * 256 + tid;        // chunk = mt*64 + lane'
            int mt = c >> 6;
            int cl = c & 63;
            int cn = cl & 15, cq = cl >> 4;
            size_t aoff = (size_t)(r0 + mt * 16 + cn) * E_DIM + k0 + cq * 8;
            gl_lds16(&xh[aoff], &Ah[c * 8]);
            if (lo) gl_lds16(&xl[aoff], &Al[c * 8]);
            size_t boff = (size_t)(c0 + mt * 16 + cn) * E_DIM + k0 + cq * 8;
            gl_lds16(&wth[boff], &Bh[c * 8]);
            if (lo) gl_lds16(&wtl[boff], &Bl[c * 8]);
        }
        __syncthreads();

        bf16x8 ah[4], al[4];
        #pragma unroll
        for (int i = 0; i < 4; i++) {
            ah[i] = *(bf16x8*)&Ah[((wr * 4 + i) * 64 + lane) * 8];
            if (lo) al[i] = *(bf16x8*)&Al[((wr * 4 + i) * 64 + lane) * 8];
        }
        #pragma unroll
        for (int j = 0; j < 4; j++) {
            bf16x8 bh = *(bf16x8*)&Bh[((wc * 4 + j) * 64 + lane) * 8];
            if (lo) {
                bf16x8 bl = *(bf16x8*)&Bl[((wc * 4 + j) * 64 + lane) * 8];
                #pragma unroll
                for (int i = 0; i < 4; i++) {
                    acc[i][j] = MFMA16(ah[i], bh, acc[i][j]);
                    acc[i][j] = MFMA16(al[i], bh, acc[i][j]);
                    acc[i][j] = MFMA16(ah[i], bl, acc[i][j]);
                }
            } else {
                #pragma unroll
                for (int i = 0; i < 4; i++)
                    acc[i][j] = MFMA16(ah[i], bh, acc[i][j]);
            }
        }
    }

    // epilogue
    const float qscale = 0.02209708691f;   // 1/sqrt(2048)
    #pragma unroll
    for (int i = 0; i < 4; i++) {
        int rowb = r0 + wr * 64 + i * 16 + qd * 4;   // + r
        #pragma unroll
        for (int j = 0; j < 4; j++) {
            int col = c0 + wc * 64 + j * 16 + n16;
            int h = (col & 1023) >> 6, d = col & 63;
            if (m == 2) {
                int b = rowb >> 11, t = rowb & 2047;
                u16x4 pv;
                #pragma unroll
                for (int r = 0; r < 4; r++) pv[r] = f2bf(acc[i][j][r]);
                *(u16x4*)&vt[((size_t)((h * 2 + b) * 64 + d)) * T_LEN + t] = pv;
            } else {
                u16* oh = (m == 0) ? qh : kh;
                u16* ol = (m == 0) ? ql : kl;
                float sc = (m == 0) ? qscale : 1.0f;
                #pragma unroll
                for (int r = 0; r < 4; r++) {
                    int row = rowb + r;
                    int b = row >> 11, t = row & 2047;
                    float f = acc[i][j][r] * sc;
                    u16 hi = f2bf(f);
                    size_t o = ((size_t)((h * 2 + b) * T_LEN + t)) * HD + d;
                    oh[o] = hi;
                    ol[o] = f2bf(f - bf2f(hi));
                }
            }
        }
    }
}

// ---------------------------------------------------------------------------
// Flash attention, bf16 MFMA, hi/lo QK^T. Q frags in registers; K/V staged
// via global_load_lds (no conversion VALU). Writes att as bf16 [b][t][1024].
// ---------------------------------------------------------------------------
__global__ __launch_bounds__(256) void attn_kernel(
    const u16* __restrict__ qh, const u16* __restrict__ ql,
    const u16* __restrict__ kh, const u16* __restrict__ kl,
    const u16* __restrict__ vt, u16* __restrict__ attb)
{
    const int hb = blockIdx.y;       // 0..31
    const int h = hb >> 1, b = hb & 1;
    const int t0 = blockIdx.x * 64;

    const size_t base_tk = (size_t)(h * 2 + b) * T_LEN * HD;   // q/k arrays
    const size_t base_v  = (size_t)(h * 2 + b) * HD * T_LEN;   // vt array

    __shared__ __align__(16) u16 BKh[4096], BKl[4096], BV[4096], AP[4096]; // 32KB

    const int tid  = threadIdx.x;
    const int lane = tid & 63;
    const int w    = tid >> 6;
    const int qd   = lane >> 4;
    const int n16  = lane & 15;

    // Q A-frags straight to registers (scale already folded in)
    bf16x8 aqh[2], aql[2];
    #pragma unroll
    for (int ks = 0; ks < 2; ks++) {
        size_t o = base_tk + (size_t)(t0 + w * 16 + n16) * HD + ks * 32 + qd * 8;
        aqh[ks] = *(const bf16x8*)&qh[o];
        aql[ks] = *(const bf16x8*)&ql[o];
    }

    f32x4 o4[4];
    #pragma unroll
    for (int c = 0; c < 4; c++) o4[c] = (f32x4){0.f, 0.f, 0.f, 0.f};
    float mr[4] = {-1e30f, -1e30f, -1e30f, -1e30f};
    float lr[4] = {0.f, 0.f, 0.f, 0.f};

    bf16x8 ones;
    #pragma unroll
    for (int j = 0; j < 8; j++) ones[j] = (short)0x3F80;

    for (int st = 0; st < T_LEN / 64; st++) {
        __syncthreads();   // prev PV reads of BV/AP done; buffers free

        // async stage K (hi/lo) and V
        #pragma unroll
        for (int rep = 0; rep < 2; rep++) {
            int c = rep * 256 + tid;          // chunk = (nt*2+ks)*64 + lane'
            int nt = c >> 7, ks = (c >> 6) & 1;
            int cl = c & 63;
            int cn = cl & 15, cq = cl >> 4;
            size_t ko = base_tk + (size_t)(st * 64 + nt * 16 + cn) * HD + ks * 32 + cq * 8;
            gl_lds16(&kh[ko], &BKh[c * 8]);
            gl_lds16(&kl[ko], &BKl[c * 8]);
            size_t vo = base_v + (size_t)(nt * 16 + cn) * T_LEN + st * 64 + ks * 32 + cq * 8;
            gl_lds16(&vt[vo], &BV[c * 8]);
        }
        __syncthreads();   // K,V resident

        // S = Q K^T (3-term hi/lo)
        f32x4 s[4];
        #pragma unroll
        for (int c = 0; c < 4; c++) s[c] = (f32x4){0.f, 0.f, 0.f, 0.f};
        #pragma unroll
        for (int ks = 0; ks < 2; ks++) {
            #pragma unroll
            for (int c = 0; c < 4; c++) {
                bf16x8 bh = *(bf16x8*)&BKh[((c * 2 + ks) * 64 + lane) * 8];
                bf16x8 bl = *(bf16x8*)&BKl[((c * 2 + ks) * 64 + lane) * 8];
                s[c] = MFMA16(aqh[ks], bh, s[c]);
                s[c] = MFMA16(aql[ks], bh, s[c]);
                s[c] = MFMA16(aqh[ks], bl, s[c]);
            }
        }

        // online softmax
        float rm[4];
        #pragma unroll
        for (int r = 0; r < 4; r++)
            rm[r] = fmaxf(fmaxf(s[0][r], s[1][r]), fmaxf(s[2][r], s[3][r]));
        #pragma unroll
        for (int r = 0; r < 4; r++) {
            rm[r] = fmaxf(rm[r], __shfl_xor(rm[r], 1));
            rm[r] = fmaxf(rm[r], __shfl_xor(rm[r], 2));
            rm[r] = fmaxf(rm[r], __shfl_xor(rm[r], 4));
            rm[r] = fmaxf(rm[r], __shfl_xor(rm[r], 8));
        }
        float al4[4];
        #pragma unroll
        for (int r = 0; r < 4; r++) {
            float nm = fmaxf(mr[r], rm[r]);
            al4[r] = __expf(mr[r] - nm);
            mr[r] = nm;
        }
        #pragma unroll
        for (int c = 0; c < 4; c++) {
            #pragma unroll
            for (int r = 0; r < 4; r++) {
                float p = __expf(s[c][r] - mr[r]);
                int col = c * 16 + n16;
                int ks = col >> 5, qp = (col >> 3) & 3, j = col & 7;
                int lp = (qp << 4) | (qd * 4 + r);
                AP[((w * 2 + ks) * 64 + lp) * 8 + j] = (short)f2bf(p);
            }
        }
        #pragma unroll
        for (int c = 0; c < 4; c++)
            #pragma unroll
            for (int r = 0; r < 4; r++) o4[c][r] *= al4[r];
        __syncthreads();

        // O += P V ; row-sum via ones-MFMA
        bf16x8 ap0 = *(bf16x8*)&AP[((w * 2 + 0) * 64 + lane) * 8];
        bf16x8 ap1 = *(bf16x8*)&AP[((w * 2 + 1) * 64 + lane) * 8];
        f32x4 sm = (f32x4){0.f, 0.f, 0.f, 0.f};
        sm = MFMA16(ap0, ones, sm);
        sm = MFMA16(ap1, ones, sm);
        #pragma unroll
        for (int c = 0; c < 4; c++) {
            bf16x8 bv0 = *(bf16x8*)&BV[((c * 2 + 0) * 64 + lane) * 8];
            bf16x8 bv1 = *(bf16x8*)&BV[((c * 2 + 1) * 64 + lane) * 8];
            o4[c] = MFMA16(ap0, bv0, o4[c]);
            o4[c] = MFMA16(ap1, bv1, o4[c]);
        }
        #pragma unroll
        for (int r = 0; r < 4; r++) lr[r] = lr[r] * al4[r] + sm[r];
    }

    float inv[4];
    #pragma unroll
    for (int r = 0; r < 4; r++) inv[r] = 1.f / lr[r];
    #pragma unroll
    for (int c = 0; c < 4; c++) {
        #pragma unroll
        for (int r = 0; r < 4; r++) {
            int row = t0 + w * 16 + qd * 4 + r;
            attb[(size_t)(b * T_LEN + row) * E_DIM + h * HD + c * 16 + n16] =
                f2bf(o4[c][r] * inv[r]);
        }
    }
}

// ---------------------------------------------------------------------------
// Output projection: out(4096x1024 fp32) = attb(bf16) @ Wo^T (wob bf16).
// 128x128 tile, BK=64, plain bf16 MFMA. grid (8, 32).
// ---------------------------------------------------------------------------
__global__ __launch_bounds__(256) void outproj_mfma_kernel(
    const u16* __restrict__ attb, const u16* __restrict__ wob,
    float* __restrict__ out)
{
    const int c0 = blockIdx.x * 128;
    const int r0 = blockIdx.y * 128;

    __shared__ __align__(16) u16 As[8192], Bs[8192];   // 16KB each

    const int tid = threadIdx.x;
    const int w = tid >> 6, lane = tid & 63;
    const int qd = lane >> 4, n16 = lane & 15;
    const int wr = w >> 1, wc = w & 1;

    f32x4 acc[4][4];
    #pragma unroll
    for (int i = 0; i < 4; i++)
        #pragma unroll
        for (int j = 0; j < 4; j++) acc[i][j] = (f32x4){0.f, 0.f, 0.f, 0.f};

    for (int k0 = 0; k0 < E_DIM; k0 += 64) {
        __syncthreads();
        #pragma unroll
        for (int rep = 0; rep < 4; rep++) {
            int c = rep * 256 + tid;          // chunk = (mt*2+ks)*64 + lane'
            int mt = c >> 7, ks = (c >> 6) & 1;
            int cl = c & 63;
            int cn = cl & 15, cq = cl >> 4;
            gl_lds16(&attb[(size_t)(r0 + mt * 16 + cn) * E_DIM + k0 + ks * 32 + cq * 8],
                     &As[c * 8]);
            gl_lds16(&wob[(size_t)(c0 + mt * 16 + cn) * E_DIM + k0 + ks * 32 + cq * 8],
                     &Bs[c * 8]);
        }
        __syncthreads();

        #pragma unroll
        for (int ks = 0; ks < 2; ks++) {
            bf16x8 a[4];
            #pragma unroll
            for (int i = 0; i < 4; i++)
                a[i] = *(bf16x8*)&As[(((wr * 4 + i) * 2 + ks) * 64 + lane) * 8];
            #pragma unroll
            for (int j = 0; j < 4; j++) {
                bf16x8 bb = *(bf16x8*)&Bs[(((wc * 4 + j) * 2 + ks) * 64 + lane) * 8];
                #pragma unroll
                for (int i = 0; i < 4; i++)
                    acc[i][j] = MFMA16(a[i], bb, acc[i][j]);
            }
        }
    }

    #pragma unroll
    for (int i = 0; i < 4; i++) {
        #pragma unroll
        for (int r = 0; r < 4; r++) {
            int row = r0 + wr * 64 + i * 16 + qd * 4 + r;
            #pragma unroll
            for (int j = 0; j < 4; j++) {
                int col = c0 + wc * 64 + j * 16 + n16;
                out[(size_t)row * E_DIM + col] = acc[i][j][r];
            }
        }
    }
}

extern "C" void kernel_launch(void* const* d_in, const int* in_sizes, int n_in,
                              void* d_out, int out_size, void* d_ws, size_t ws_size,
                              hipStream_t stream)
{
    const float* x  = (const float*)d_in[0];
    const float* Wq = (const float*)d_in[1];
    const float* Wk = (const float*)d_in[2];
    const float* Wv = (const float*)d_in[3];
    const float* Wo = (const float*)d_in[4];
    float* out = (float*)d_out;

    const size_t NX = (size_t)4096 * 1024;   // x elems
    const size_t NW = (size_t)3072 * 1024;   // all-heads weight elems
    const size_t NO = (size_t)1024 * 1024;   // Wo elems
    const size_t NQ = (size_t)H_NUM * B_NUM * T_LEN * HD;  // 4,194,304

    u16* xh  = (u16*)d_ws;
    u16* xl  = xh + NX;
    u16* wth = xl + NX;
    u16* wtl = wth + NW;
    u16* wob = wtl + NW;
    u16* qh  = wob + NO;
    u16* ql  = qh + NQ;
    u16* kh  = ql + NQ;
    u16* kl  = kh + NQ;
    u16* vt  = kl + NQ;
    u16* attb = xh;   // alias: xh dead after qkv_mfma, attb written by attn

    convert_x_kernel<<<4096, 256, 0, stream>>>(x, xh, xl);
    convert_w_kernel<<<768, 256, 0, stream>>>(Wq, Wk, Wv, wth, wtl);
    convert_wo_kernel<<<1024, 256, 0, stream>>>(Wo, wob);

    dim3 g1(24, 32);
    qkv_mfma_kernel<<<g1, 256, 0, stream>>>(xh, xl, wth, wtl, qh, ql, kh, kl, vt);

    dim3 g2(T_LEN / 64, H_NUM * B_NUM);
    attn_kernel<<<g2, 256, 0, stream>>>(qh, ql, kh, kl, vt, attb);

    dim3 g3(E_DIM / 128, 4096 / 128);
    outproj_mfma_kernel<<<g3, 256, 0, stream>>>(attb, wob, out);
}

// Round 4
// 340.667 us; speedup vs baseline: 4.5790x; 1.0864x over previous
//
#include <hip/hip_runtime.h>
#include <math.h>

#define E_DIM 1024
#define H_NUM 16
#define HD 64
#define B_NUM 2
#define T_LEN 2048

typedef unsigned short u16;
typedef short bf16x8 __attribute__((ext_vector_type(8)));
typedef float f32x4 __attribute__((ext_vector_type(4)));
typedef unsigned short u16x4 __attribute__((ext_vector_type(4)));

#define MFMA16(a, b, c) __builtin_amdgcn_mfma_f32_16x16x32_bf16(a, b, c, 0, 0, 0)

__device__ __forceinline__ u16 f2bf(float f) {
    unsigned u = __float_as_uint(f);
    u += 0x7FFFu + ((u >> 16) & 1u);   // RNE
    return (u16)(u >> 16);
}
__device__ __forceinline__ float bf2f(u16 b) {
    return __uint_as_float(((unsigned)b) << 16);
}
// async global->LDS 16B copy. LDS dest must be wave-uniform base + lane*16;
// all call sites index LDS chunks linearly in tid, which satisfies that.
__device__ __forceinline__ void gl_lds16(const void* g, void* l) {
    __builtin_amdgcn_global_load_lds(
        (const __attribute__((address_space(1))) unsigned int*)g,
        (__attribute__((address_space(3))) unsigned int*)l, 16, 0, 0);
}

// ---------------------------------------------------------------------------
// convert x (fp32 [4096][1024]) -> xh, xl bf16 hi/lo, same layout
// ---------------------------------------------------------------------------
__global__ __launch_bounds__(256) void convert_x_kernel(
    const float* __restrict__ x, u16* __restrict__ xh, u16* __restrict__ xl)
{
    int i = (blockIdx.x * 256 + threadIdx.x) * 4;
    float4 f = *(const float4*)&x[i];
    float fv[4] = {f.x, f.y, f.z, f.w};
    u16x4 h, l;
    #pragma unroll
    for (int j = 0; j < 4; j++) {
        u16 hi = f2bf(fv[j]);
        h[j] = hi;
        l[j] = f2bf(fv[j] - bf2f(hi));
    }
    *(u16x4*)&xh[i] = h;
    *(u16x4*)&xl[i] = l;
}

// ---------------------------------------------------------------------------
// convert Wq/Wk/Wv ([16][1024][64] each) -> wth/wtl [3072][1024] bf16,
// WT[col=m*1024+h*64+i][e] = Wm[h][e][i]   (transpose via LDS tile)
// ---------------------------------------------------------------------------
__global__ __launch_bounds__(256) void convert_w_kernel(
    const float* __restrict__ Wq, const float* __restrict__ Wk, const float* __restrict__ Wv,
    u16* __restrict__ wth, u16* __restrict__ wtl)
{
    const int bx = blockIdx.x;
    const int m = bx >> 8, h = (bx >> 4) & 15, e0 = (bx & 15) * 64;
    const float* W = (m == 0 ? Wq : (m == 1 ? Wk : Wv));

    __shared__ u16 Th[64][65];
    __shared__ u16 Tl[64][65];
    const int tid = threadIdx.x;

    #pragma unroll
    for (int j = 0; j < 16; j++) {
        int idx = j * 256 + tid;
        int e = idx >> 6, i = idx & 63;
        float f = W[((size_t)h * E_DIM + e0 + e) * HD + i];
        u16 hi = f2bf(f);
        Th[i][e] = hi;
        Tl[i][e] = f2bf(f - bf2f(hi));
    }
    __syncthreads();
    #pragma unroll
    for (int j = 0; j < 16; j++) {
        int idx = j * 256 + tid;
        int i = idx >> 6, e = idx & 63;
        size_t o = (size_t)(m * 1024 + h * 64 + i) * E_DIM + e0 + e;
        wth[o] = Th[i][e];
        wtl[o] = Tl[i][e];
    }
}

// ---------------------------------------------------------------------------
// convert Wo (fp32 [1024][1024]) -> wob bf16 same layout
// ---------------------------------------------------------------------------
__global__ __launch_bounds__(256) void convert_wo_kernel(
    const float* __restrict__ Wo, u16* __restrict__ wob)
{
    int i = (blockIdx.x * 256 + threadIdx.x) * 4;
    float4 f = *(const float4*)&Wo[i];
    float fv[4] = {f.x, f.y, f.z, f.w};
    u16x4 h;
    #pragma unroll
    for (int j = 0; j < 4; j++) h[j] = f2bf(fv[j]);
    *(u16x4*)&wob[i] = h;
}

// ---------------------------------------------------------------------------
// Fused QKV GEMM: C(4096 x 3072) = X(4096x1024) @ WT^T, bf16 MFMA,
// 3-term hi/lo for q/k columns, 1-term for v columns.
// ---------------------------------------------------------------------------
__global__ __launch_bounds__(256) void qkv_mfma_kernel(
    const u16* __restrict__ xh, const u16* __restrict__ xl,
    const u16* __restrict__ wth, const u16* __restrict__ wtl,
    u16* __restrict__ qh, u16* __restrict__ ql,
    u16* __restrict__ kh, u16* __restrict__ kl,
    u16* __restrict__ vt)
{
    const int c0 = blockIdx.x * 128;
    const int r0 = blockIdx.y * 128;
    const int m  = c0 >> 10;            // 0=q 1=k 2=v
    const bool lo = (m != 2);

    __shared__ __align__(16) u16 Ah[4096], Al[4096];
    __shared__ __align__(16) u16 Bh[4096], Bl[4096];

    const int tid = threadIdx.x;
    const int w = tid >> 6, lane = tid & 63;
    const int qd = lane >> 4, n16 = lane & 15;
    const int wr = w >> 1, wc = w & 1;

    f32x4 acc[4][4];
    #pragma unroll
    for (int i = 0; i < 4; i++)
        #pragma unroll
        for (int j = 0; j < 4; j++) acc[i][j] = (f32x4){0.f, 0.f, 0.f, 0.f};

    for (int k0 = 0; k0 < E_DIM; k0 += 32) {
        __syncthreads();
        #pragma unroll
        for (int rep = 0; rep < 2; rep++) {
            int c = rep * 256 + tid;
            int mt = c >> 6;
            int cl = c & 63;
            int cn = cl & 15, cq = cl >> 4;
            size_t aoff = (size_t)(r0 + mt * 16 + cn) * E_DIM + k0 + cq * 8;
            gl_lds16(&xh[aoff], &Ah[c * 8]);
            if (lo) gl_lds16(&xl[aoff], &Al[c * 8]);
            size_t boff = (size_t)(c0 + mt * 16 + cn) * E_DIM + k0 + cq * 8;
            gl_lds16(&wth[boff], &Bh[c * 8]);
            if (lo) gl_lds16(&wtl[boff], &Bl[c * 8]);
        }
        __syncthreads();

        bf16x8 ah[4], al[4];
        #pragma unroll
        for (int i = 0; i < 4; i++) {
            ah[i] = *(bf16x8*)&Ah[((wr * 4 + i) * 64 + lane) * 8];
            if (lo) al[i] = *(bf16x8*)&Al[((wr * 4 + i) * 64 + lane) * 8];
        }
        #pragma unroll
        for (int j = 0; j < 4; j++) {
            bf16x8 bh = *(bf16x8*)&Bh[((wc * 4 + j) * 64 + lane) * 8];
            if (lo) {
                bf16x8 bl = *(bf16x8*)&Bl[((wc * 4 + j) * 64 + lane) * 8];
                #pragma unroll
                for (int i = 0; i < 4; i++) {
                    acc[i][j] = MFMA16(ah[i], bh, acc[i][j]);
                    acc[i][j] = MFMA16(al[i], bh, acc[i][j]);
                    acc[i][j] = MFMA16(ah[i], bl, acc[i][j]);
                }
            } else {
                #pragma unroll
                for (int i = 0; i < 4; i++)
                    acc[i][j] = MFMA16(ah[i], bh, acc[i][j]);
            }
        }
    }

    const float qscale = 0.02209708691f;   // 1/sqrt(2048)
    #pragma unroll
    for (int i = 0; i < 4; i++) {
        int rowb = r0 + wr * 64 + i * 16 + qd * 4;
        #pragma unroll
        for (int j = 0; j < 4; j++) {
            int col = c0 + wc * 64 + j * 16 + n16;
            int h = (col & 1023) >> 6, d = col & 63;
            if (m == 2) {
                int b = rowb >> 11, t = rowb & 2047;
                u16x4 pv;
                #pragma unroll
                for (int r = 0; r < 4; r++) pv[r] = f2bf(acc[i][j][r]);
                *(u16x4*)&vt[((size_t)((h * 2 + b) * 64 + d)) * T_LEN + t] = pv;
            } else {
                u16* oh = (m == 0) ? qh : kh;
                u16* ol = (m == 0) ? ql : kl;
                float sc = (m == 0) ? qscale : 1.0f;
                #pragma unroll
                for (int r = 0; r < 4; r++) {
                    int row = rowb + r;
                    int b = row >> 11, t = row & 2047;
                    float f = acc[i][j][r] * sc;
                    u16 hi = f2bf(f);
                    size_t o = ((size_t)((h * 2 + b) * T_LEN + t)) * HD + d;
                    oh[o] = hi;
                    ol[o] = f2bf(f - bf2f(hi));
                }
            }
        }
    }
}

// ---------------------------------------------------------------------------
// Flash attention, transposed formulation:
//   S^T = K Q^T   (A = K-frag from LDS, B = Q^T-frag in registers)
//   O^T = V^T P^T (A = V^T-frag from LDS (vt [d][t]), B = P^T via wave-private LDS)
// C-layout of S^T puts each query in a lane column (col=n16): softmax state
// (m, l, alpha) is a per-lane scalar; l cross-lane reduction deferred to the
// epilogue. P transform: 4x ds_write_b64 (2-way banks, free) + 2x ds_read_b128,
// wave-private -> no barrier. Replaces 16 scalar u16 writes + 16 shuffles +
// ones-MFMA of the previous version.
// ---------------------------------------------------------------------------
__global__ __launch_bounds__(256) void attn_kernel(
    const u16* __restrict__ qh, const u16* __restrict__ ql,
    const u16* __restrict__ kh, const u16* __restrict__ kl,
    const u16* __restrict__ vt, u16* __restrict__ attb)
{
    const int hb = blockIdx.y;       // 0..31
    const int h = hb >> 1, b = hb & 1;
    const int t0 = blockIdx.x * 64;

    const size_t base_tk = (size_t)(h * 2 + b) * T_LEN * HD;   // q/k arrays
    const size_t base_v  = (size_t)(h * 2 + b) * HD * T_LEN;   // vt array

    __shared__ __align__(16) u16 BKh[4096], BKl[4096], BV[4096];  // 24KB
    __shared__ __align__(16) u16 PT[4][16][72];                   // 9KB, wave-private

    const int tid  = threadIdx.x;
    const int lane = tid & 63;
    const int w    = tid >> 6;
    const int qd   = lane >> 4;
    const int n16  = lane & 15;

    // Q^T B-frags in registers: lane holds Q[t0 + w*16 + n16][ks*32 + qd*8 + j]
    bf16x8 bqh[2], bql[2];
    #pragma unroll
    for (int ks = 0; ks < 2; ks++) {
        size_t o = base_tk + (size_t)(t0 + w * 16 + n16) * HD + ks * 32 + qd * 8;
        bqh[ks] = *(const bf16x8*)&qh[o];
        bql[ks] = *(const bf16x8*)&ql[o];
    }

    f32x4 o4[4];   // o4[dt][r] = O^T[dt*16 + qd*4 + r][query n16]
    #pragma unroll
    for (int dt = 0; dt < 4; dt++) o4[dt] = (f32x4){0.f, 0.f, 0.f, 0.f};
    float mr = -1e30f, lr = 0.f;

    for (int st = 0; st < T_LEN / 64; st++) {
        __syncthreads();   // prev-iter BV/BK reads done; buffers free

        // async stage K (hi/lo) and V^T — chunk layouts unchanged from R3
        #pragma unroll
        for (int rep = 0; rep < 2; rep++) {
            int c = rep * 256 + tid;          // chunk = (nt*2+ks)*64 + lane'
            int nt = c >> 7, ks = (c >> 6) & 1;
            int cl = c & 63;
            int cn = cl & 15, cq = cl >> 4;
            size_t ko = base_tk + (size_t)(st * 64 + nt * 16 + cn) * HD + ks * 32 + cq * 8;
            gl_lds16(&kh[ko], &BKh[c * 8]);
            gl_lds16(&kl[ko], &BKl[c * 8]);
            size_t vo = base_v + (size_t)(nt * 16 + cn) * T_LEN + st * 64 + ks * 32 + cq * 8;
            gl_lds16(&vt[vo], &BV[c * 8]);
        }
        __syncthreads();   // K,V resident

        // S^T = K Q^T, 3-term hi/lo: kh*qh + kh*ql + kl*qh
        f32x4 s[4];
        #pragma unroll
        for (int c = 0; c < 4; c++) s[c] = (f32x4){0.f, 0.f, 0.f, 0.f};
        #pragma unroll
        for (int ks = 0; ks < 2; ks++) {
            #pragma unroll
            for (int c = 0; c < 4; c++) {
                bf16x8 akh = *(bf16x8*)&BKh[((c * 2 + ks) * 64 + lane) * 8];
                bf16x8 akl = *(bf16x8*)&BKl[((c * 2 + ks) * 64 + lane) * 8];
                s[c] = MFMA16(akh, bqh[ks], s[c]);
                s[c] = MFMA16(akh, bql[ks], s[c]);
                s[c] = MFMA16(akl, bqh[ks], s[c]);
            }
        }

        // online softmax: query = column n16 -> per-lane scalar state
        float tmax = s[0][0];
        #pragma unroll
        for (int c = 0; c < 4; c++)
            #pragma unroll
            for (int r = 0; r < 4; r++) tmax = fmaxf(tmax, s[c][r]);
        tmax = fmaxf(tmax, __shfl_xor(tmax, 16));
        tmax = fmaxf(tmax, __shfl_xor(tmax, 32));
        float nm = fmaxf(mr, tmax);
        float al = __expf(mr - nm);
        mr = nm;

        float psum = 0.f;
        #pragma unroll
        for (int c = 0; c < 4; c++) {
            u16x4 pk;
            #pragma unroll
            for (int r = 0; r < 4; r++) {
                float p = __expf(s[c][r] - nm);
                psum += p;
                pk[r] = f2bf(p);
            }
            *(u16x4*)&PT[w][n16][c * 16 + qd * 4] = pk;   // ds_write_b64
        }
        lr = lr * al + psum;
        #pragma unroll
        for (int dt = 0; dt < 4; dt++)
            #pragma unroll
            for (int r = 0; r < 4; r++) o4[dt][r] *= al;

        // O^T += V^T P^T  (PT is wave-private: no barrier needed)
        #pragma unroll
        for (int ks = 0; ks < 2; ks++) {
            bf16x8 bp = *(bf16x8*)&PT[w][n16][ks * 32 + qd * 8];   // ds_read_b128
            #pragma unroll
            for (int dt = 0; dt < 4; dt++) {
                bf16x8 av = *(bf16x8*)&BV[((dt * 2 + ks) * 64 + lane) * 8];
                o4[dt] = MFMA16(av, bp, o4[dt]);
            }
        }
    }

    // epilogue: finish l reduction across quads, normalize, store d-contiguous
    lr += __shfl_xor(lr, 16);
    lr += __shfl_xor(lr, 32);
    float inv = 1.f / lr;
    int row = t0 + w * 16 + n16;
    #pragma unroll
    for (int dt = 0; dt < 4; dt++) {
        u16x4 ov;
        #pragma unroll
        for (int r = 0; r < 4; r++) ov[r] = f2bf(o4[dt][r] * inv);
        *(u16x4*)&attb[(size_t)(b * T_LEN + row) * E_DIM + h * HD + dt * 16 + qd * 4] = ov;
    }
}

// ---------------------------------------------------------------------------
// Output projection: out(4096x1024 fp32) = attb(bf16) @ Wo^T (wob bf16).
// ---------------------------------------------------------------------------
__global__ __launch_bounds__(256) void outproj_mfma_kernel(
    const u16* __restrict__ attb, const u16* __restrict__ wob,
    float* __restrict__ out)
{
    const int c0 = blockIdx.x * 128;
    const int r0 = blockIdx.y * 128;

    __shared__ __align__(16) u16 As[8192], Bs[8192];

    const int tid = threadIdx.x;
    const int w = tid >> 6, lane = tid & 63;
    const int qd = lane >> 4, n16 = lane & 15;
    const int wr = w >> 1, wc = w & 1;

    f32x4 acc[4][4];
    #pragma unroll
    for (int i = 0; i < 4; i++)
        #pragma unroll
        for (int j = 0; j < 4; j++) acc[i][j] = (f32x4){0.f, 0.f, 0.f, 0.f};

    for (int k0 = 0; k0 < E_DIM; k0 += 64) {
        __syncthreads();
        #pragma unroll
        for (int rep = 0; rep < 4; rep++) {
            int c = rep * 256 + tid;
            int mt = c >> 7, ks = (c >> 6) & 1;
            int cl = c & 63;
            int cn = cl & 15, cq = cl >> 4;
            gl_lds16(&attb[(size_t)(r0 + mt * 16 + cn) * E_DIM + k0 + ks * 32 + cq * 8],
                     &As[c * 8]);
            gl_lds16(&wob[(size_t)(c0 + mt * 16 + cn) * E_DIM + k0 + ks * 32 + cq * 8],
                     &Bs[c * 8]);
        }
        __syncthreads();

        #pragma unroll
        for (int ks = 0; ks < 2; ks++) {
            bf16x8 a[4];
            #pragma unroll
            for (int i = 0; i < 4; i++)
                a[i] = *(bf16x8*)&As[(((wr * 4 + i) * 2 + ks) * 64 + lane) * 8];
            #pragma unroll
            for (int j = 0; j < 4; j++) {
                bf16x8 bb = *(bf16x8*)&Bs[(((wc * 4 + j) * 2 + ks) * 64 + lane) * 8];
                #pragma unroll
                for (int i = 0; i < 4; i++)
                    acc[i][j] = MFMA16(a[i], bb, acc[i][j]);
            }
        }
    }

    #pragma unroll
    for (int i = 0; i < 4; i++) {
        #pragma unroll
        for (int r = 0; r < 4; r++) {
            int row = r0 + wr * 64 + i * 16 + qd * 4 + r;
            #pragma unroll
            for (int j = 0; j < 4; j++) {
                int col = c0 + wc * 64 + j * 16 + n16;
                out[(size_t)row * E_DIM + col] = acc[i][j][r];
            }
        }
    }
}

extern "C" void kernel_launch(void* const* d_in, const int* in_sizes, int n_in,
                              void* d_out, int out_size, void* d_ws, size_t ws_size,
                              hipStream_t stream)
{
    const float* x  = (const float*)d_in[0];
    const float* Wq = (const float*)d_in[1];
    const float* Wk = (const float*)d_in[2];
    const float* Wv = (const float*)d_in[3];
    const float* Wo = (const float*)d_in[4];
    float* out = (float*)d_out;

    const size_t NX = (size_t)4096 * 1024;
    const size_t NW = (size_t)3072 * 1024;
    const size_t NO = (size_t)1024 * 1024;
    const size_t NQ = (size_t)H_NUM * B_NUM * T_LEN * HD;

    u16* xh  = (u16*)d_ws;
    u16* xl  = xh + NX;
    u16* wth = xl + NX;
    u16* wtl = wth + NW;
    u16* wob = wtl + NW;
    u16* qh  = wob + NO;
    u16* ql  = qh + NQ;
    u16* kh  = ql + NQ;
    u16* kl  = kh + NQ;
    u16* vt  = kl + NQ;
    u16* attb = xh;   // alias: xh dead after qkv_mfma

    convert_x_kernel<<<4096, 256, 0, stream>>>(x, xh, xl);
    convert_w_kernel<<<768, 256, 0, stream>>>(Wq, Wk, Wv, wth, wtl);
    convert_wo_kernel<<<1024, 256, 0, stream>>>(Wo, wob);

    dim3 g1(24, 32);
    qkv_mfma_kernel<<<g1, 256, 0, stream>>>(xh, xl, wth, wtl, qh, ql, kh, kl, vt);

    dim3 g2(T_LEN / 64, H_NUM * B_NUM);
    attn_kernel<<<g2, 256, 0, stream>>>(qh, ql, kh, kl, vt, attb);

    dim3 g3(E_DIM / 128, 4096 / 128);
    outproj_mfma_kernel<<<g3, 256, 0, stream>>>(attb, wob, out);
}

// Round 5
// 340.370 us; speedup vs baseline: 4.5830x; 1.0009x over previous
//
#include <hip/hip_runtime.h>
#include <math.h>

#define E_DIM 1024
#define H_NUM 16
#define HD 64
#define B_NUM 2
#define T_LEN 2048

typedef unsigned short u16;
typedef short bf16x8 __attribute__((ext_vector_type(8)));
typedef float f32x4 __attribute__((ext_vector_type(4)));
typedef unsigned short u16x4 __attribute__((ext_vector_type(4)));
typedef unsigned short u16x8 __attribute__((ext_vector_type(8)));

#define MFMA16(a, b, c) __builtin_amdgcn_mfma_f32_16x16x32_bf16(a, b, c, 0, 0, 0)

__device__ __forceinline__ u16 f2bf(float f) {
    unsigned u = __float_as_uint(f);
    u += 0x7FFFu + ((u >> 16) & 1u);   // RNE
    return (u16)(u >> 16);
}
__device__ __forceinline__ float bf2f(u16 b) {
    return __uint_as_float(((unsigned)b) << 16);
}
// async global->LDS 16B copy. LDS dest must be wave-uniform base + lane*16;
// all call sites index LDS chunks linearly in tid, which satisfies that.
__device__ __forceinline__ void gl_lds16(const void* g, void* l) {
    __builtin_amdgcn_global_load_lds(
        (const __attribute__((address_space(1))) unsigned int*)g,
        (__attribute__((address_space(3))) unsigned int*)l, 16, 0, 0);
}

// ---------------------------------------------------------------------------
// convert x (fp32 [4096][1024]) -> xh, xl bf16 hi/lo, same layout
// ---------------------------------------------------------------------------
__global__ __launch_bounds__(256) void convert_x_kernel(
    const float* __restrict__ x, u16* __restrict__ xh, u16* __restrict__ xl)
{
    int i = (blockIdx.x * 256 + threadIdx.x) * 4;
    float4 f = *(const float4*)&x[i];
    float fv[4] = {f.x, f.y, f.z, f.w};
    u16x4 h, l;
    #pragma unroll
    for (int j = 0; j < 4; j++) {
        u16 hi = f2bf(fv[j]);
        h[j] = hi;
        l[j] = f2bf(fv[j] - bf2f(hi));
    }
    *(u16x4*)&xh[i] = h;
    *(u16x4*)&xl[i] = l;
}

// ---------------------------------------------------------------------------
// convert Wq/Wk/Wv ([16][1024][64] each) -> wth/wtl [3072][1024] bf16,
// WT[col=m*1024+h*64+i][e] = Wm[h][e][i]   (transpose via LDS tile)
// ---------------------------------------------------------------------------
__global__ __launch_bounds__(256) void convert_w_kernel(
    const float* __restrict__ Wq, const float* __restrict__ Wk, const float* __restrict__ Wv,
    u16* __restrict__ wth, u16* __restrict__ wtl)
{
    const int bx = blockIdx.x;
    const int m = bx >> 8, h = (bx >> 4) & 15, e0 = (bx & 15) * 64;
    const float* W = (m == 0 ? Wq : (m == 1 ? Wk : Wv));

    __shared__ u16 Th[64][65];
    __shared__ u16 Tl[64][65];
    const int tid = threadIdx.x;

    #pragma unroll
    for (int j = 0; j < 16; j++) {
        int idx = j * 256 + tid;
        int e = idx >> 6, i = idx & 63;
        float f = W[((size_t)h * E_DIM + e0 + e) * HD + i];
        u16 hi = f2bf(f);
        Th[i][e] = hi;
        Tl[i][e] = f2bf(f - bf2f(hi));
    }
    __syncthreads();
    #pragma unroll
    for (int j = 0; j < 16; j++) {
        int idx = j * 256 + tid;
        int i = idx >> 6, e = idx & 63;
        size_t o = (size_t)(m * 1024 + h * 64 + i) * E_DIM + e0 + e;
        wth[o] = Th[i][e];
        wtl[o] = Tl[i][e];
    }
}

// ---------------------------------------------------------------------------
// convert Wo (fp32 [1024][1024]) -> wob bf16 same layout
// ---------------------------------------------------------------------------
__global__ __launch_bounds__(256) void convert_wo_kernel(
    const float* __restrict__ Wo, u16* __restrict__ wob)
{
    int i = (blockIdx.x * 256 + threadIdx.x) * 4;
    float4 f = *(const float4*)&Wo[i];
    float fv[4] = {f.x, f.y, f.z, f.w};
    u16x4 h;
    #pragma unroll
    for (int j = 0; j < 4; j++) h[j] = f2bf(fv[j]);
    *(u16x4*)&wob[i] = h;
}

// ---------------------------------------------------------------------------
// Fused QKV GEMM, retiled for occupancy: 128(M) x 64(N) tiles, BK=32.
// grid (48, 32) = 1536 blocks -> 6 blocks/CU static (was 768/3).
// cols: bx 0..15 = q heads, 16..31 = k heads, 32..47 = v heads (one head/tile).
// q/k: 3-term hi/lo MFMA; v: 1-term + in-LDS transpose epilogue for
// coalesced [d][t] stores (v-blocks have slack: 1/3 the MFMA work).
// ---------------------------------------------------------------------------
__global__ __launch_bounds__(256) void qkv_mfma_kernel(
    const u16* __restrict__ xh, const u16* __restrict__ xl,
    const u16* __restrict__ wth, const u16* __restrict__ wtl,
    u16* __restrict__ qh, u16* __restrict__ ql,
    u16* __restrict__ kh, u16* __restrict__ kl,
    u16* __restrict__ vt)
{
    const int bx = blockIdx.x;
    const int c0 = bx * 64;            // global col
    const int r0 = blockIdx.y * 128;   // global row
    const int m  = bx >> 4;            // 0=q 1=k 2=v
    const int h  = bx & 15;            // head
    const bool lo = (m != 2);

    // staging: A 128x32 hi/lo (4096 u16 each), B 64x32 hi/lo (2048 each) = 24KB
    __shared__ __align__(16) u16 SM[12288];
    u16* Ah = SM;            // 4096
    u16* Al = SM + 4096;     // 4096
    u16* Bh = SM + 8192;     // 2048
    u16* Bl = SM + 10240;    // 2048

    const int tid = threadIdx.x;
    const int w = tid >> 6, lane = tid & 63;
    const int qd = lane >> 4, n16 = lane & 15;
    const int wr = w >> 1, wc = w & 1;   // wave covers rows wr*64..+63, cols wc*32..+31

    f32x4 acc[4][2];
    #pragma unroll
    for (int i = 0; i < 4; i++)
        #pragma unroll
        for (int j = 0; j < 2; j++) acc[i][j] = (f32x4){0.f, 0.f, 0.f, 0.f};

    for (int k0 = 0; k0 < E_DIM; k0 += 32) {
        __syncthreads();
        // A: 512 chunks (x2 hi/lo)
        #pragma unroll
        for (int rep = 0; rep < 2; rep++) {
            int c = rep * 256 + tid;          // 0..511: chunk = mt*64 + lane'
            int mt = c >> 6;
            int cl = c & 63;
            int cn = cl & 15, cq = cl >> 4;
            size_t aoff = (size_t)(r0 + mt * 16 + cn) * E_DIM + k0 + cq * 8;
            gl_lds16(&xh[aoff], &Ah[c * 8]);
            if (lo) gl_lds16(&xl[aoff], &Al[c * 8]);
        }
        // B: 256 chunks (x2 hi/lo)
        {
            int c = tid;                       // 0..255: chunk = nt*64 + lane'
            int nt = c >> 6;
            int cl = c & 63;
            int cn = cl & 15, cq = cl >> 4;
            size_t boff = (size_t)(c0 + nt * 16 + cn) * E_DIM + k0 + cq * 8;
            gl_lds16(&wth[boff], &Bh[c * 8]);
            if (lo) gl_lds16(&wtl[boff], &Bl[c * 8]);
        }
        __syncthreads();

        bf16x8 ah[4], al_[4];
        #pragma unroll
        for (int i = 0; i < 4; i++) {
            ah[i] = *(bf16x8*)&Ah[((wr * 4 + i) * 64 + lane) * 8];
            if (lo) al_[i] = *(bf16x8*)&Al[((wr * 4 + i) * 64 + lane) * 8];
        }
        #pragma unroll
        for (int j = 0; j < 2; j++) {
            bf16x8 bh = *(bf16x8*)&Bh[((wc * 2 + j) * 64 + lane) * 8];
            if (lo) {
                bf16x8 bl = *(bf16x8*)&Bl[((wc * 2 + j) * 64 + lane) * 8];
                #pragma unroll
                for (int i = 0; i < 4; i++) {
                    acc[i][j] = MFMA16(ah[i], bh, acc[i][j]);
                    acc[i][j] = MFMA16(al_[i], bh, acc[i][j]);
                    acc[i][j] = MFMA16(ah[i], bl, acc[i][j]);
                }
            } else {
                #pragma unroll
                for (int i = 0; i < 4; i++)
                    acc[i][j] = MFMA16(ah[i], bh, acc[i][j]);
            }
        }
    }

    if (m == 2) {
        // ---- v epilogue: transpose 128(t) x 64(d) tile through LDS, then
        //      coalesced 16B stores along t into vt[h][b][d][t]. ----
        __syncthreads();                        // all waves done reading SM
        const int VS = 136;                     // u16 stride per d-row (2-way banks)
        #pragma unroll
        for (int i = 0; i < 4; i++) {
            int tl = wr * 64 + i * 16 + qd * 4; // local t base of this frag row
            #pragma unroll
            for (int j = 0; j < 2; j++) {
                int d = wc * 32 + j * 16 + n16;
                u16x4 pv;
                #pragma unroll
                for (int r = 0; r < 4; r++) pv[r] = f2bf(acc[i][j][r]);
                *(u16x4*)&SM[d * VS + tl] = pv;
            }
        }
        __syncthreads();
        const int b = r0 >> 11, t0g = r0 & 2047;
        const size_t vbase = (size_t)(h * 2 + b) * HD * T_LEN;
        #pragma unroll
        for (int rep = 0; rep < 4; rep++) {
            int c = rep * 256 + tid;            // 1024 chunks: d(64) x 16 t-chunks
            int d = c >> 4, toff = (c & 15) * 8;
            u16x8 v8 = *(u16x8*)&SM[d * VS + toff];
            *(u16x8*)&vt[vbase + (size_t)d * T_LEN + t0g + toff] = v8;
        }
    } else {
        // ---- q/k epilogue: hi/lo split, [h][b][t][d] layout ----
        const float sc = (m == 0) ? 0.02209708691f : 1.0f;   // q pre-scaled 1/sqrt(T)
        u16* oh = (m == 0) ? qh : kh;
        u16* ol = (m == 0) ? ql : kl;
        #pragma unroll
        for (int i = 0; i < 4; i++) {
            int rowb = r0 + wr * 64 + i * 16 + qd * 4;
            #pragma unroll
            for (int j = 0; j < 2; j++) {
                int d = wc * 32 + j * 16 + n16;
                #pragma unroll
                for (int r = 0; r < 4; r++) {
                    int row = rowb + r;
                    int b = row >> 11, t = row & 2047;
                    float f = acc[i][j][r] * sc;
                    u16 hi = f2bf(f);
                    size_t o = ((size_t)((h * 2 + b) * T_LEN + t)) * HD + d;
                    oh[o] = hi;
                    ol[o] = f2bf(f - bf2f(hi));
                }
            }
        }
    }
}

// ---------------------------------------------------------------------------
// Flash attention, transposed formulation (unchanged from R4):
//   S^T = K Q^T ; O^T = V^T P^T with wave-private P^T LDS round-trip.
// ---------------------------------------------------------------------------
__global__ __launch_bounds__(256) void attn_kernel(
    const u16* __restrict__ qh, const u16* __restrict__ ql,
    const u16* __restrict__ kh, const u16* __restrict__ kl,
    const u16* __restrict__ vt, u16* __restrict__ attb)
{
    const int hb = blockIdx.y;       // 0..31
    const int h = hb >> 1, b = hb & 1;
    const int t0 = blockIdx.x * 64;

    const size_t base_tk = (size_t)(h * 2 + b) * T_LEN * HD;
    const size_t base_v  = (size_t)(h * 2 + b) * HD * T_LEN;

    __shared__ __align__(16) u16 BKh[4096], BKl[4096], BV[4096];  // 24KB
    __shared__ __align__(16) u16 PT[4][16][72];                   // 9KB, wave-private

    const int tid  = threadIdx.x;
    const int lane = tid & 63;
    const int w    = tid >> 6;
    const int qd   = lane >> 4;
    const int n16  = lane & 15;

    bf16x8 bqh[2], bql[2];
    #pragma unroll
    for (int ks = 0; ks < 2; ks++) {
        size_t o = base_tk + (size_t)(t0 + w * 16 + n16) * HD + ks * 32 + qd * 8;
        bqh[ks] = *(const bf16x8*)&qh[o];
        bql[ks] = *(const bf16x8*)&ql[o];
    }

    f32x4 o4[4];
    #pragma unroll
    for (int dt = 0; dt < 4; dt++) o4[dt] = (f32x4){0.f, 0.f, 0.f, 0.f};
    float mr = -1e30f, lr = 0.f;

    for (int st = 0; st < T_LEN / 64; st++) {
        __syncthreads();

        #pragma unroll
        for (int rep = 0; rep < 2; rep++) {
            int c = rep * 256 + tid;
            int nt = c >> 7, ks = (c >> 6) & 1;
            int cl = c & 63;
            int cn = cl & 15, cq = cl >> 4;
            size_t ko = base_tk + (size_t)(st * 64 + nt * 16 + cn) * HD + ks * 32 + cq * 8;
            gl_lds16(&kh[ko], &BKh[c * 8]);
            gl_lds16(&kl[ko], &BKl[c * 8]);
            size_t vo = base_v + (size_t)(nt * 16 + cn) * T_LEN + st * 64 + ks * 32 + cq * 8;
            gl_lds16(&vt[vo], &BV[c * 8]);
        }
        __syncthreads();

        f32x4 s[4];
        #pragma unroll
        for (int c = 0; c < 4; c++) s[c] = (f32x4){0.f, 0.f, 0.f, 0.f};
        #pragma unroll
        for (int ks = 0; ks < 2; ks++) {
            #pragma unroll
            for (int c = 0; c < 4; c++) {
                bf16x8 akh = *(bf16x8*)&BKh[((c * 2 + ks) * 64 + lane) * 8];
                bf16x8 akl = *(bf16x8*)&BKl[((c * 2 + ks) * 64 + lane) * 8];
                s[c] = MFMA16(akh, bqh[ks], s[c]);
                s[c] = MFMA16(akh, bql[ks], s[c]);
                s[c] = MFMA16(akl, bqh[ks], s[c]);
            }
        }

        float tmax = s[0][0];
        #pragma unroll
        for (int c = 0; c < 4; c++)
            #pragma unroll
            for (int r = 0; r < 4; r++) tmax = fmaxf(tmax, s[c][r]);
        tmax = fmaxf(tmax, __shfl_xor(tmax, 16));
        tmax = fmaxf(tmax, __shfl_xor(tmax, 32));
        float nm = fmaxf(mr, tmax);
        float al = __expf(mr - nm);
        mr = nm;

        float psum = 0.f;
        #pragma unroll
        for (int c = 0; c < 4; c++) {
            u16x4 pk;
            #pragma unroll
            for (int r = 0; r < 4; r++) {
                float p = __expf(s[c][r] - nm);
                psum += p;
                pk[r] = f2bf(p);
            }
            *(u16x4*)&PT[w][n16][c * 16 + qd * 4] = pk;
        }
        lr = lr * al + psum;
        #pragma unroll
        for (int dt = 0; dt < 4; dt++)
            #pragma unroll
            for (int r = 0; r < 4; r++) o4[dt][r] *= al;

        #pragma unroll
        for (int ks = 0; ks < 2; ks++) {
            bf16x8 bp = *(bf16x8*)&PT[w][n16][ks * 32 + qd * 8];
            #pragma unroll
            for (int dt = 0; dt < 4; dt++) {
                bf16x8 av = *(bf16x8*)&BV[((dt * 2 + ks) * 64 + lane) * 8];
                o4[dt] = MFMA16(av, bp, o4[dt]);
            }
        }
    }

    lr += __shfl_xor(lr, 16);
    lr += __shfl_xor(lr, 32);
    float inv = 1.f / lr;
    int row = t0 + w * 16 + n16;
    #pragma unroll
    for (int dt = 0; dt < 4; dt++) {
        u16x4 ov;
        #pragma unroll
        for (int r = 0; r < 4; r++) ov[r] = f2bf(o4[dt][r] * inv);
        *(u16x4*)&attb[(size_t)(b * T_LEN + row) * E_DIM + h * HD + dt * 16 + qd * 4] = ov;
    }
}

// ---------------------------------------------------------------------------
// Output projection: out(4096x1024 fp32) = attb(bf16) @ Wo^T (wob bf16).
// ---------------------------------------------------------------------------
__global__ __launch_bounds__(256) void outproj_mfma_kernel(
    const u16* __restrict__ attb, const u16* __restrict__ wob,
    float* __restrict__ out)
{
    const int c0 = blockIdx.x * 128;
    const int r0 = blockIdx.y * 128;

    __shared__ __align__(16) u16 As[8192], Bs[8192];

    const int tid = threadIdx.x;
    const int w = tid >> 6, lane = tid & 63;
    const int qd = lane >> 4, n16 = lane & 15;
    const int wr = w >> 1, wc = w & 1;

    f32x4 acc[4][4];
    #pragma unroll
    for (int i = 0; i < 4; i++)
        #pragma unroll
        for (int j = 0; j < 4; j++) acc[i][j] = (f32x4){0.f, 0.f, 0.f, 0.f};

    for (int k0 = 0; k0 < E_DIM; k0 += 64) {
        __syncthreads();
        #pragma unroll
        for (int rep = 0; rep < 4; rep++) {
            int c = rep * 256 + tid;
            int mt = c >> 7, ks = (c >> 6) & 1;
            int cl = c & 63;
            int cn = cl & 15, cq = cl >> 4;
            gl_lds16(&attb[(size_t)(r0 + mt * 16 + cn) * E_DIM + k0 + ks * 32 + cq * 8],
                     &As[c * 8]);
            gl_lds16(&wob[(size_t)(c0 + mt * 16 + cn) * E_DIM + k0 + ks * 32 + cq * 8],
                     &Bs[c * 8]);
        }
        __syncthreads();

        #pragma unroll
        for (int ks = 0; ks < 2; ks++) {
            bf16x8 a[4];
            #pragma unroll
            for (int i = 0; i < 4; i++)
                a[i] = *(bf16x8*)&As[(((wr * 4 + i) * 2 + ks) * 64 + lane) * 8];
            #pragma unroll
            for (int j = 0; j < 4; j++) {
                bf16x8 bb = *(bf16x8*)&Bs[(((wc * 4 + j) * 2 + ks) * 64 + lane) * 8];
                #pragma unroll
                for (int i = 0; i < 4; i++)
                    acc[i][j] = MFMA16(a[i], bb, acc[i][j]);
            }
        }
    }

    #pragma unroll
    for (int i = 0; i < 4; i++) {
        #pragma unroll
        for (int r = 0; r < 4; r++) {
            int row = r0 + wr * 64 + i * 16 + qd * 4 + r;
            #pragma unroll
            for (int j = 0; j < 4; j++) {
                int col = c0 + wc * 64 + j * 16 + n16;
                out[(size_t)row * E_DIM + col] = acc[i][j][r];
            }
        }
    }
}

extern "C" void kernel_launch(void* const* d_in, const int* in_sizes, int n_in,
                              void* d_out, int out_size, void* d_ws, size_t ws_size,
                              hipStream_t stream)
{
    const float* x  = (const float*)d_in[0];
    const float* Wq = (const float*)d_in[1];
    const float* Wk = (const float*)d_in[2];
    const float* Wv = (const float*)d_in[3];
    const float* Wo = (const float*)d_in[4];
    float* out = (float*)d_out;

    const size_t NX = (size_t)4096 * 1024;
    const size_t NW = (size_t)3072 * 1024;
    const size_t NO = (size_t)1024 * 1024;
    const size_t NQ = (size_t)H_NUM * B_NUM * T_LEN * HD;

    u16* xh  = (u16*)d_ws;
    u16* xl  = xh + NX;
    u16* wth = xl + NX;
    u16* wtl = wth + NW;
    u16* wob = wtl + NW;
    u16* qh  = wob + NO;
    u16* ql  = qh + NQ;
    u16* kh  = ql + NQ;
    u16* kl  = kh + NQ;
    u16* vt  = kl + NQ;
    u16* attb = xh;   // alias: xh dead after qkv_mfma

    convert_x_kernel<<<4096, 256, 0, stream>>>(x, xh, xl);
    convert_w_kernel<<<768, 256, 0, stream>>>(Wq, Wk, Wv, wth, wtl);
    convert_wo_kernel<<<1024, 256, 0, stream>>>(Wo, wob);

    dim3 g1(48, 32);
    qkv_mfma_kernel<<<g1, 256, 0, stream>>>(xh, xl, wth, wtl, qh, ql, kh, kl, vt);

    dim3 g2(T_LEN / 64, H_NUM * B_NUM);
    attn_kernel<<<g2, 256, 0, stream>>>(qh, ql, kh, kl, vt, attb);

    dim3 g3(E_DIM / 128, 4096 / 128);
    outproj_mfma_kernel<<<g3, 256, 0, stream>>>(attb, wob, out);
}